// Round 12
// baseline (379.019 us; speedup 1.0000x reference)
//
#include <hip/hip_runtime.h>

// VQ-VAE quantization: z [16384 x 512] f32, codebook [8192 x 512] f32.
// out = concat(z_st [16384*512] f32, vq_loss [1] f32).
//
// R4: MX-fp8 (e4m3, K=128 scaled MFMA) GEMM; packed (dist|idx) u32 argmin.
// R13 (148.5µs gemm): 256thr/4-wave 64x64 tiles, XCD remap, dbuf, no spill.
// R14: counted vmcnt + setprio = NO change -> barrier drain wasn't the stall.
// R15 (this): persistent blocks. 512 blocks (exactly 2/CU), each owns ONE
// mtile (A-rows L2-hot for its whole life) and walks 16 ktiles
// (ktile = 4t + b>>7). The counted-vmcnt pipeline runs continuously across
// tile boundaries: next tile's stage in flight through this tile's epilogue,
// prologue paid once not 16x. Es prefetched 1 tile ahead into regs
// (uniform bundles: dt0 = 8 stage + 4 es = 12, else 8 -> exact immediates).
// Loss: back to R0-style fire-and-forget atomicAdd (90.3µs others, beat
// both partials+reduce 104 and acq-rel last-block 134). 3 launches.

#define M_ROWS 16384
#define K_CODES 8192
#define DIM 512
#define BM 128
#define BN 128
#define BK 128                 // fp8 bytes per K-step (one 16x16x128 MFMA)
#define NT (K_CODES / BN)      // 64 ktiles
#define OUT0_SIZE (M_ROWS * DIM)
#define GB_BLOCKS 1024

typedef int   i32x8 __attribute__((ext_vector_type(8)));
typedef float f32x4 __attribute__((ext_vector_type(4)));

template <bool HI>
__device__ __forceinline__ int pk8(float a, float b, int old) {
    return __builtin_amdgcn_cvt_pk_fp8_f32(a, b, old, HI);
}

__device__ __forceinline__ void gload_lds(const unsigned char* g, unsigned char* l) {
    __builtin_amdgcn_global_load_lds((const __attribute__((address_space(1))) void*)g,
                                     (__attribute__((address_space(3))) void*)l, 16, 0, 0);
}

// ---- kernel 1: fused converts ------------------------------------------
__global__ __launch_bounds__(256) void convert_all(
    const float* __restrict__ z, const float* __restrict__ cb,
    unsigned char* __restrict__ z8, unsigned char* __restrict__ cb8,
    float* __restrict__ enorm, float* __restrict__ lossSlot)
{
    const int tid = threadIdx.x;
    if (blockIdx.x == 0 && tid == 0) *lossSlot = 0.f;   // gather accumulates
    if (blockIdx.x < K_CODES / 4) {
        const int w = tid >> 6, lane = tid & 63;
        const int row = blockIdx.x * 4 + w;
        const float* src = cb + (size_t)row * DIM + lane * 8;
        float4 a = *(const float4*)(src);
        float4 b = *(const float4*)(src + 4);
        float ns = a.x * a.x + a.y * a.y + a.z * a.z + a.w * a.w
                 + b.x * b.x + b.y * b.y + b.z * b.z + b.w * b.w;
        const float S = 8192.0f;                 // exact power of 2
        int lo = 0, hi = 0;
        lo = pk8<false>(a.x * S, a.y * S, lo); lo = pk8<true>(a.z * S, a.w * S, lo);
        hi = pk8<false>(b.x * S, b.y * S, hi); hi = pk8<true>(b.z * S, b.w * S, hi);
        *(int2*)(cb8 + (size_t)row * DIM + lane * 8) = make_int2(lo, hi);
        for (int m = 32; m; m >>= 1) ns += __shfl_down(ns, m, 64);
        if (lane == 0) enorm[row] = S * ns;      // 8192 * ||e||^2 (f32-exact norm)
    } else {
        size_t i = ((size_t)(blockIdx.x - K_CODES / 4) * 256 + tid) * 8;
        float4 a = *(const float4*)(z + i);
        float4 b = *(const float4*)(z + i + 4);
        int lo = 0, hi = 0;
        lo = pk8<false>(a.x, a.y, lo); lo = pk8<true>(a.z, a.w, lo);
        hi = pk8<false>(b.x, b.y, hi); hi = pk8<true>(b.z, b.w, hi);
        *(int2*)(z8 + i) = make_int2(lo, hi);
    }
}

// ---- kernel 2: persistent MX-fp8 GEMM + packed-argmin ------------------
__global__ __launch_bounds__(256, 2) void gemm_argmin(
    const unsigned char* __restrict__ z8, const unsigned char* __restrict__ cbb,
    const float* __restrict__ enorm, unsigned int* __restrict__ candV)
{
    __shared__ alignas(32) unsigned char As[2 * BM * BK];  // 32 KB dbuf
    __shared__ alignas(32) unsigned char Bs[2 * BN * BK];  // 32 KB dbuf
    __shared__ unsigned int cU[BM][2];

    const int tid = threadIdx.x;
    const int lane = tid & 63;
    const int w = tid >> 6;             // 0..3
    const int b = blockIdx.x;           // 0..511, persistent (2/CU)
    const int xcd = b & 7;
    const int m4 = (b >> 3) & 15;
    const int k0 = b >> 7;              // 0..3
    const int mbase = (xcd * 16 + m4) * BM;   // fixed A-slice per block

    const int rA = lane >> 3;           // row within 8-row chunk
    const int jG = ((lane & 7) ^ rA) * 16;  // pre-swizzled global 16B chunk
    const int quad = lane >> 4;
    const int l15 = lane & 15;
    const int sw = l15 & 7;
    const int rw = (w >> 1) * 64;       // wave row quadrant
    const int cw = (w & 1) * 64;        // wave col quadrant
    // Chunks c0=(2q)^sw, c1=c0^1 = one aligned 32B block (R3-proven: the
    // per-lane half-swap is identical for A and B -> dot product exact).
    const int t32 = ((quad << 1) ^ (sw & 6)) * 16;

    // Exactly 8 gload_lds per thread per STAGE (vmcnt bookkeeping).
#define STAGE(buf, nb_, dt_) do {                                             \
    _Pragma("unroll")                                                         \
    for (int i_ = 0; i_ < 4; ++i_) {                                          \
        int c_ = w * 4 + i_;                                                  \
        int row_ = c_ * 8 + rA;                                               \
        int col_ = (dt_) * BK + jG;                                           \
        gload_lds(z8 + (size_t)(mbase + row_) * DIM + col_,                   \
                  As + (buf) * (BM * BK) + c_ * 1024 + lane * 16);            \
        gload_lds(cbb + (size_t)((nb_) + row_) * DIM + col_,                  \
                  Bs + (buf) * (BN * BK) + c_ * 1024 + lane * 16);            \
    } } while (0)

#define MFMA_PHASE(buf)                                                       \
    do {                                                                      \
        const unsigned char* Ab = As + (buf) * (BM * BK);                     \
        const unsigned char* Bb = Bs + (buf) * (BN * BK);                     \
        __builtin_amdgcn_s_setprio(1);                                        \
        _Pragma("unroll")                                                     \
        for (int h = 0; h < 2; ++h) {                                         \
            i32x8 bf0 = *(const i32x8*)(Bb + (cw + (h*2+0)*16 + l15)*BK + t32); \
            i32x8 bf1 = *(const i32x8*)(Bb + (cw + (h*2+1)*16 + l15)*BK + t32); \
            _Pragma("unroll")                                                 \
            for (int rf = 0; rf < 4; ++rf) {                                  \
                i32x8 a = *(const i32x8*)(Ab + (rw + rf*16 + l15)*BK + t32);  \
                acc[rf*4 + h*2 + 0] = __builtin_amdgcn_mfma_scale_f32_16x16x128_f8f6f4( \
                    a, bf0, acc[rf*4 + h*2 + 0], 0, 0, 0, 0x7F7F7F7F, 0, 0x7F7F7F7F); \
                acc[rf*4 + h*2 + 1] = __builtin_amdgcn_mfma_scale_f32_16x16x128_f8f6f4( \
                    a, bf1, acc[rf*4 + h*2 + 1], 0, 0, 0, 0x7F7F7F7F, 0, 0x7F7F7F7F); \
            }                                                                 \
        }                                                                     \
        __builtin_amdgcn_s_setprio(0);                                        \
    } while (0)

#define WAITB(n)                                                              \
    asm volatile("s_waitcnt vmcnt(" #n ")" ::: "memory");                     \
    __builtin_amdgcn_sched_barrier(0);                                        \
    __builtin_amdgcn_s_barrier()

#define ENDB()                                                                \
    __builtin_amdgcn_s_barrier();                                             \
    __builtin_amdgcn_sched_barrier(0)

    float es_c[4], es_n[4];
    {
        const int nb0 = k0 * BN;        // ktile(0) = k0
#pragma unroll
        for (int cf = 0; cf < 4; ++cf) es_c[cf] = enorm[nb0 + cw + cf * 16 + l15];
        STAGE(0, nb0, 0);
    }
    __syncthreads();   // full drain once: buf0 ready, vmcnt = 0

#pragma unroll 1
    for (int t = 0; t < 16; ++t) {
        const int kt = t * 4 + k0;
        const int nb = kt * BN;
        const int ktn = ((t + 1) & 15) * 4 + k0;   // wrapped: t=15 loads are dummy
        const int nbn = ktn * BN;

        f32x4 acc[16];
#pragma unroll
        for (int i = 0; i < 16; ++i) acc[i] = (f32x4){0.f, 0.f, 0.f, 0.f};

        // dt0: compute buf0; issue stage(buf1,dt1) + es(next) = 12 ops
        STAGE(1, nb, 1);
#pragma unroll
        for (int cf = 0; cf < 4; ++cf) es_n[cf] = enorm[nbn + cw + cf * 16 + l15];
        WAITB(12);
        MFMA_PHASE(0);
        ENDB();
        // dt1
        STAGE(0, nb, 2);
        WAITB(8);
        MFMA_PHASE(1);
        ENDB();
        // dt2
        STAGE(1, nb, 3);
        WAITB(8);
        MFMA_PHASE(0);
        ENDB();
        // dt3: prefetch next tile's dt0 (dummy at t=15, valid addresses)
        STAGE(0, nbn, 0);
        WAITB(8);
        MFMA_PHASE(1);
        ENDB();

        // epilogue: per-row argmin over this tile's 128 cols.
        // C/D layout: col = lane&15, row = quad*4 + reg.
#pragma unroll
        for (int rf = 0; rf < 4; ++rf) {
#pragma unroll
            for (int r = 0; r < 4; ++r) {
                float bv = 3.4e38f; int bi = 0;
#pragma unroll
                for (int cf = 0; cf < 4; ++cf) {
                    int col = cw + cf * 16 + l15;
                    float dist = fmaf(-2.0f, acc[rf * 4 + cf][r], es_c[cf]);
                    if (dist < bv) { bv = dist; bi = col; }  // strict <
                }
                unsigned u = __builtin_bit_cast(unsigned, bv);
                u ^= ((unsigned)(((int)u) >> 31)) | 0x80000000u;
                unsigned key = (u & 0xFFFFE000u) | (unsigned)(nb + bi);
#pragma unroll
                for (int m = 1; m < 16; m <<= 1) {
                    unsigned o = __shfl_xor(key, m, 64);
                    key = o < key ? o : key;
                }
                if (l15 == 0) cU[rw + rf * 16 + quad * 4 + r][w & 1] = key;
            }
        }
        asm volatile("s_waitcnt lgkmcnt(0)" ::: "memory");  // cU writes visible
        __builtin_amdgcn_s_barrier();       // no vmcnt drain: prefetch lives on
        if (tid < BM) {
            unsigned ka = cU[tid][0], kb = cU[tid][1];
            candV[(size_t)kt * M_ROWS + mbase + tid] = ka < kb ? ka : kb;
        }
#pragma unroll
        for (int cf = 0; cf < 4; ++cf) es_c[cf] = es_n[cf];
    }
#undef STAGE
#undef MFMA_PHASE
#undef WAITB
#undef ENDB
}

// ---- kernel 3: candidate-reduce + gather + ST output + loss atomic -----
// 4 waves/block, wave owns a row/iter: umin over the 64 packed candidates
// (lane = ktile), then 128 float4 slots. One atomicAdd per block (R0-style).
__global__ __launch_bounds__(256) void gather_out(
    const float* __restrict__ z, const float* __restrict__ cb,
    const unsigned int* __restrict__ candV, float* __restrict__ out)
{
    __shared__ float red[4];
    const int tid = threadIdx.x;
    const int w = tid >> 6, lane = tid & 63;
    float lsum = 0.f;
#pragma unroll
    for (int it = 0; it < M_ROWS / (GB_BLOCKS * 4); ++it) {
        int row = (it * GB_BLOCKS + blockIdx.x) * 4 + w;
        unsigned key = candV[(size_t)lane * M_ROWS + row];
#pragma unroll
        for (int m = 1; m < 64; m <<= 1) {
            unsigned o = __shfl_xor(key, m, 64);
            key = o < key ? o : key;
        }
        int k = (int)(key & 8191u);
#pragma unroll
        for (int j = 0; j < 2; ++j) {
            int slot = lane + j * 64;
            float4 zv = ((const float4*)(z + (size_t)row * DIM))[slot];
            float4 cv = ((const float4*)(cb + (size_t)k * DIM))[slot];
            float dx = cv.x - zv.x, dy = cv.y - zv.y;
            float dz2 = cv.z - zv.z, dw = cv.w - zv.w;
            float4 o = {zv.x + dx, zv.y + dy, zv.z + dz2, zv.w + dw};  // z + sg(zq-z)
            ((float4*)(out + (size_t)row * DIM))[slot] = o;
            lsum += dx * dx + dy * dy + dz2 * dz2 + dw * dw;
        }
    }
    for (int m = 32; m; m >>= 1) lsum += __shfl_down(lsum, m, 64);
    if (lane == 0) red[w] = lsum;
    __syncthreads();
    if (tid == 0) {
        float t = (red[0] + red[1]) + (red[2] + red[3]);
        atomicAdd(out + OUT0_SIZE, t * (1.1f / (float)OUT0_SIZE));  // vq_loss = 1.1*mean
    }
}

extern "C" void kernel_launch(void* const* d_in, const int* in_sizes, int n_in,
                              void* d_out, int out_size, void* d_ws, size_t ws_size,
                              hipStream_t stream) {
    const float* z = (const float*)d_in[0];     // 16*1024*512
    const float* cb = (const float*)d_in[1];    // 8192*512
    float* out = (float*)d_out;                 // 8388608 + 1
    char* ws = (char*)d_ws;

    // ws layout (bytes)
    unsigned char* z8   = (unsigned char*)(ws);               //  8,388,608
    unsigned char* cb8  = (unsigned char*)(ws + 8388608);     //  4,194,304
    float* enorm        = (float*)(ws + 12582912);            //     32,768
    unsigned int* candV = (unsigned int*)(ws + 12615680);     //  4,194,304

    convert_all<<<K_CODES / 4 + M_ROWS * DIM / 2048, 256, 0, stream>>>(
        z, cb, z8, cb8, enorm, out + OUT0_SIZE);
    gemm_argmin<<<512, 256, 0, stream>>>(z8, cb8, enorm, candV);
    gather_out<<<GB_BLOCKS, 256, 0, stream>>>(z, cb, candV, out);
}

// Round 13
// 258.490 us; speedup vs baseline: 1.4663x; 1.4663x over previous
//
#include <hip/hip_runtime.h>

// VQ-VAE quantization: z [16384 x 512] f32, codebook [8192 x 512] f32.
// out = concat(z_st [16384*512] f32, vq_loss [1] f32).
//
// R4: MX-fp8 (e4m3, K=128 scaled MFMA) GEMM; packed (dist|idx) u32 argmin.
// R13 (=148.5µs gemm, best): 256thr/4-wave 64x64 tiles, XCD remap, dbuf,
// unroll-1 + 2-B-frag hoist (spill-free). R14 counted-vmcnt: null.
// R15 persistent: regressed (spill + B re-stream). REVERTED.
// R16 (this): R13 gemm byte-for-byte + 3-launch tail: convert_all zeroes
// loss slot, gather_out does one plain atomicAdd per block (R0-measured
// 90.3µs others vs 104 partials+reduce), reduce_loss launch dropped.

#define M_ROWS 16384
#define K_CODES 8192
#define DIM 512
#define BM 128
#define BN 128
#define BK 128                 // fp8 bytes per K-step (one 16x16x128 MFMA)
#define NT (K_CODES / BN)      // 64 ktiles
#define OUT0_SIZE (M_ROWS * DIM)
#define GB_BLOCKS 1024

typedef int   i32x8 __attribute__((ext_vector_type(8)));
typedef float f32x4 __attribute__((ext_vector_type(4)));

template <bool HI>
__device__ __forceinline__ int pk8(float a, float b, int old) {
    return __builtin_amdgcn_cvt_pk_fp8_f32(a, b, old, HI);
}

__device__ __forceinline__ void gload_lds(const unsigned char* g, unsigned char* l) {
    __builtin_amdgcn_global_load_lds((const __attribute__((address_space(1))) void*)g,
                                     (__attribute__((address_space(3))) void*)l, 16, 0, 0);
}

// ---- kernel 1: fused converts ------------------------------------------
__global__ __launch_bounds__(256) void convert_all(
    const float* __restrict__ z, const float* __restrict__ cb,
    unsigned char* __restrict__ z8, unsigned char* __restrict__ cb8,
    float* __restrict__ enorm, float* __restrict__ lossSlot)
{
    const int tid = threadIdx.x;
    if (blockIdx.x == 0 && tid == 0) *lossSlot = 0.f;   // gather accumulates
    if (blockIdx.x < K_CODES / 4) {
        const int w = tid >> 6, lane = tid & 63;
        const int row = blockIdx.x * 4 + w;
        const float* src = cb + (size_t)row * DIM + lane * 8;
        float4 a = *(const float4*)(src);
        float4 b = *(const float4*)(src + 4);
        float ns = a.x * a.x + a.y * a.y + a.z * a.z + a.w * a.w
                 + b.x * b.x + b.y * b.y + b.z * b.z + b.w * b.w;
        const float S = 8192.0f;                 // exact power of 2
        int lo = 0, hi = 0;
        lo = pk8<false>(a.x * S, a.y * S, lo); lo = pk8<true>(a.z * S, a.w * S, lo);
        hi = pk8<false>(b.x * S, b.y * S, hi); hi = pk8<true>(b.z * S, b.w * S, hi);
        *(int2*)(cb8 + (size_t)row * DIM + lane * 8) = make_int2(lo, hi);
        for (int m = 32; m; m >>= 1) ns += __shfl_down(ns, m, 64);
        if (lane == 0) enorm[row] = S * ns;      // 8192 * ||e||^2 (f32-exact norm)
    } else {
        size_t i = ((size_t)(blockIdx.x - K_CODES / 4) * 256 + tid) * 8;
        float4 a = *(const float4*)(z + i);
        float4 b = *(const float4*)(z + i + 4);
        int lo = 0, hi = 0;
        lo = pk8<false>(a.x, a.y, lo); lo = pk8<true>(a.z, a.w, lo);
        hi = pk8<false>(b.x, b.y, hi); hi = pk8<true>(b.z, b.w, hi);
        *(int2*)(z8 + i) = make_int2(lo, hi);
    }
}

// ---- kernel 2: MX-fp8 GEMM (128x128, 4 waves) + packed-argmin ----------
// R13/R10-best, byte-for-byte.
__global__ __launch_bounds__(256, 2) void gemm_argmin(
    const unsigned char* __restrict__ z8, const unsigned char* __restrict__ cbb,
    const float* __restrict__ enorm, unsigned int* __restrict__ candV)
{
    __shared__ alignas(32) unsigned char As[2 * BM * BK];  // 32 KB dbuf
    __shared__ alignas(32) unsigned char Bs[2 * BN * BK];  // 32 KB dbuf
    __shared__ float Es[BN];
    __shared__ unsigned int cU[BM][2];

    const int tid = threadIdx.x;
    const int lane = tid & 63;
    const int w = tid >> 6;             // 0..3
    // XCD remap: b&7 = XCD; XCD owns mtiles [xcd*16,xcd*16+16) (1MB A
    // slice, L2-hot); ktile advances every 128 blocks.
    const int b = blockIdx.x;
    const int xcd = b & 7;
    const int idx = b >> 3;             // 0..1023
    const int ktile = idx >> 4;         // 0..63
    const int mtile = xcd * 16 + (idx & 15);
    const int mbase = mtile * BM;
    const int nbase = ktile * BN;

    if (tid < BN) Es[tid] = enorm[nbase + tid];

    f32x4 acc[16];
#pragma unroll
    for (int i = 0; i < 16; ++i) acc[i] = (f32x4){0.f, 0.f, 0.f, 0.f};

    const int rA = lane >> 3;           // row within 8-row chunk
    const int jG = ((lane & 7) ^ rA) * 16;  // pre-swizzled global 16B chunk
    const int quad = lane >> 4;
    const int l15 = lane & 15;
    const int sw = l15 & 7;
    const int rw = (w >> 1) * 64;       // wave row quadrant
    const int cw = (w & 1) * 64;        // wave col quadrant
    // Chunks c0=(2q)^sw, c1=c0^1 = one aligned 32B block (R3-proven: the
    // per-lane half-swap is identical for A and B -> dot product exact).
    const int t32 = ((quad << 1) ^ (sw & 6)) * 16;

#define STAGE(buf, dt_) do {                                                  \
    _Pragma("unroll")                                                         \
    for (int i_ = 0; i_ < 4; ++i_) {                                          \
        int c_ = w * 4 + i_;                                                  \
        int row_ = c_ * 8 + rA;                                               \
        int col_ = (dt_) * BK + jG;                                           \
        gload_lds(z8 + (size_t)(mbase + row_) * DIM + col_,                   \
                  As + (buf) * (BM * BK) + c_ * 1024 + lane * 16);            \
        gload_lds(cbb + (size_t)(nbase + row_) * DIM + col_,                  \
                  Bs + (buf) * (BN * BK) + c_ * 1024 + lane * 16);            \
    } } while (0)

    STAGE(0, 0);
    __syncthreads();   // compiler drains vmcnt(0) before barrier -> buf0 ready

#pragma unroll 1
    for (int dt = 0; dt < 4; ++dt) {
        const int cur = dt & 1;
        if (dt < 3) STAGE(cur ^ 1, dt + 1);   // prefetch overlaps this compute
        const unsigned char* Ab = As + cur * (BM * BK);
        const unsigned char* Bb = Bs + cur * (BN * BK);
#pragma unroll
        for (int h = 0; h < 2; ++h) {         // 2 B frags live at a time
            i32x8 bf0 = *(const i32x8*)(Bb + (cw + (h * 2 + 0) * 16 + l15) * BK + t32);
            i32x8 bf1 = *(const i32x8*)(Bb + (cw + (h * 2 + 1) * 16 + l15) * BK + t32);
#pragma unroll
            for (int rf = 0; rf < 4; ++rf) {
                i32x8 a = *(const i32x8*)(Ab + (rw + rf * 16 + l15) * BK + t32);
                acc[rf * 4 + h * 2 + 0] = __builtin_amdgcn_mfma_scale_f32_16x16x128_f8f6f4(
                    a, bf0, acc[rf * 4 + h * 2 + 0],
                    0, 0, 0, 0x7F7F7F7F, 0, 0x7F7F7F7F);
                acc[rf * 4 + h * 2 + 1] = __builtin_amdgcn_mfma_scale_f32_16x16x128_f8f6f4(
                    a, bf1, acc[rf * 4 + h * 2 + 1],
                    0, 0, 0, 0x7F7F7F7F, 0, 0x7F7F7F7F);
            }
        }
        __syncthreads();   // reads done; prefetched buffer landed
    }
#undef STAGE

    // epilogue: per-row argmin over this tile's 128 cols.
    // C/D layout: col = lane&15, row = quad*4 + reg.
    // Packed key: monotone-uint(dist), low 13 bits = global code index.
    float es[4];
#pragma unroll
    for (int cf = 0; cf < 4; ++cf) es[cf] = Es[cw + cf * 16 + l15];

#pragma unroll
    for (int rf = 0; rf < 4; ++rf) {
#pragma unroll
        for (int r = 0; r < 4; ++r) {
            float bv = 3.4e38f; int bi = 0;
#pragma unroll
            for (int cf = 0; cf < 4; ++cf) {
                int col = cw + cf * 16 + l15;
                float dist = fmaf(-2.0f, acc[rf * 4 + cf][r], es[cf]);
                if (dist < bv) { bv = dist; bi = col; }  // strict <: low col on tie
            }
            unsigned u = __builtin_bit_cast(unsigned, bv);
            u ^= ((unsigned)(((int)u) >> 31)) | 0x80000000u;
            unsigned key = (u & 0xFFFFE000u) | (unsigned)(nbase + bi);
#pragma unroll
            for (int m = 1; m < 16; m <<= 1) {
                unsigned o = __shfl_xor(key, m, 64);
                key = o < key ? o : key;
            }
            if (l15 == 0) cU[rw + rf * 16 + quad * 4 + r][w & 1] = key;
        }
    }
    __syncthreads();
    if (tid < BM) {
        unsigned k0 = cU[tid][0], k1 = cU[tid][1];
        // [ktile][row] layout: 128 consecutive ints per block = full lines
        candV[(size_t)ktile * M_ROWS + mbase + tid] = k0 < k1 ? k0 : k1;
    }
}

// ---- kernel 3: candidate-reduce + gather + ST output + loss atomic -----
// 4 waves/block, wave owns a row/iter: umin over the 64 packed candidates
// (lane = ktile), then 128 float4 slots. One atomicAdd per block (R0-style,
// measured-cheapest loss tail).
__global__ __launch_bounds__(256) void gather_out(
    const float* __restrict__ z, const float* __restrict__ cb,
    const unsigned int* __restrict__ candV, float* __restrict__ out)
{
    __shared__ float red[4];
    const int tid = threadIdx.x;
    const int w = tid >> 6, lane = tid & 63;
    float lsum = 0.f;
#pragma unroll
    for (int it = 0; it < M_ROWS / (GB_BLOCKS * 4); ++it) {
        int row = (it * GB_BLOCKS + blockIdx.x) * 4 + w;
        unsigned key = candV[(size_t)lane * M_ROWS + row];
#pragma unroll
        for (int m = 1; m < 64; m <<= 1) {
            unsigned o = __shfl_xor(key, m, 64);
            key = o < key ? o : key;
        }
        int k = (int)(key & 8191u);
#pragma unroll
        for (int j = 0; j < 2; ++j) {
            int slot = lane + j * 64;
            float4 zv = ((const float4*)(z + (size_t)row * DIM))[slot];
            float4 cv = ((const float4*)(cb + (size_t)k * DIM))[slot];
            float dx = cv.x - zv.x, dy = cv.y - zv.y;
            float dz2 = cv.z - zv.z, dw = cv.w - zv.w;
            float4 o = {zv.x + dx, zv.y + dy, zv.z + dz2, zv.w + dw};  // z + sg(zq-z)
            ((float4*)(out + (size_t)row * DIM))[slot] = o;
            lsum += dx * dx + dy * dy + dz2 * dz2 + dw * dw;
        }
    }
    for (int m = 32; m; m >>= 1) lsum += __shfl_down(lsum, m, 64);
    if (lane == 0) red[w] = lsum;
    __syncthreads();
    if (tid == 0) {
        float t = (red[0] + red[1]) + (red[2] + red[3]);
        atomicAdd(out + OUT0_SIZE, t * (1.1f / (float)OUT0_SIZE));  // vq_loss = 1.1*mean
    }
}

extern "C" void kernel_launch(void* const* d_in, const int* in_sizes, int n_in,
                              void* d_out, int out_size, void* d_ws, size_t ws_size,
                              hipStream_t stream) {
    const float* z = (const float*)d_in[0];     // 16*1024*512
    const float* cb = (const float*)d_in[1];    // 8192*512
    float* out = (float*)d_out;                 // 8388608 + 1
    char* ws = (char*)d_ws;

    // ws layout (bytes)
    unsigned char* z8   = (unsigned char*)(ws);               //  8,388,608
    unsigned char* cb8  = (unsigned char*)(ws + 8388608);     //  4,194,304
    float* enorm        = (float*)(ws + 12582912);            //     32,768
    unsigned int* candV = (unsigned int*)(ws + 12615680);     //  4,194,304

    convert_all<<<K_CODES / 4 + M_ROWS * DIM / 2048, 256, 0, stream>>>(
        z, cb, z8, cb8, enorm, out + OUT0_SIZE);
    gemm_argmin<<<NT * (M_ROWS / BM), 256, 0, stream>>>(z8, cb8, enorm, candV);
    gather_out<<<GB_BLOCKS, 256, 0, stream>>>(z, cb, candV, out);
}

// Round 14
// 249.270 us; speedup vs baseline: 1.5205x; 1.0370x over previous
//
#include <hip/hip_runtime.h>

// VQ-VAE quantization: z [16384 x 512] f32, codebook [8192 x 512] f32.
// out = concat(z_st [16384*512] f32, vq_loss [1] f32).
//
// R4: MX-fp8 (e4m3, K=128 scaled MFMA) GEMM; packed (dist|idx) u32 argmin.
// R13/R16 (147µs gemm, stable best): 256thr/4-wave 64x64 tiles, XCD remap,
// dbuf, unroll-1 + 2-B-frag hoist, spill-free.
// R17 (this): candV array eliminated. Packed keys are u32-min-reducible ->
// gemm epilogue atomicMin's directly into candMin[16384] (2M atomics to
// 16K L2 addresses = trivial rate; deterministic; ties = lowest index by
// construction). gather_out's 64-line scatter + 6-shfl reduce becomes one
// uniform dword read -> pure streaming. cU staging + barrier + candV
// store deleted from gemm. convert_all inits candMin (blocks 0-63).

#define M_ROWS 16384
#define K_CODES 8192
#define DIM 512
#define BM 128
#define BN 128
#define BK 128                 // fp8 bytes per K-step (one 16x16x128 MFMA)
#define NT (K_CODES / BN)      // 64 ktiles
#define OUT0_SIZE (M_ROWS * DIM)
#define GB_BLOCKS 1024

typedef int   i32x8 __attribute__((ext_vector_type(8)));
typedef float f32x4 __attribute__((ext_vector_type(4)));

template <bool HI>
__device__ __forceinline__ int pk8(float a, float b, int old) {
    return __builtin_amdgcn_cvt_pk_fp8_f32(a, b, old, HI);
}

__device__ __forceinline__ void gload_lds(const unsigned char* g, unsigned char* l) {
    __builtin_amdgcn_global_load_lds((const __attribute__((address_space(1))) void*)g,
                                     (__attribute__((address_space(3))) void*)l, 16, 0, 0);
}

// ---- kernel 1: fused converts + candMin init ---------------------------
__global__ __launch_bounds__(256) void convert_all(
    const float* __restrict__ z, const float* __restrict__ cb,
    unsigned char* __restrict__ z8, unsigned char* __restrict__ cb8,
    float* __restrict__ enorm, unsigned int* __restrict__ candMin,
    float* __restrict__ lossSlot)
{
    const int tid = threadIdx.x;
    if (blockIdx.x == 0 && tid == 0) *lossSlot = 0.f;   // gather accumulates
    {   // blocks 0..63 init candMin[16384]
        int gi = blockIdx.x * 256 + tid;
        if (gi < M_ROWS) candMin[gi] = 0xFFFFFFFFu;
    }
    if (blockIdx.x < K_CODES / 4) {
        const int w = tid >> 6, lane = tid & 63;
        const int row = blockIdx.x * 4 + w;
        const float* src = cb + (size_t)row * DIM + lane * 8;
        float4 a = *(const float4*)(src);
        float4 b = *(const float4*)(src + 4);
        float ns = a.x * a.x + a.y * a.y + a.z * a.z + a.w * a.w
                 + b.x * b.x + b.y * b.y + b.z * b.z + b.w * b.w;
        const float S = 8192.0f;                 // exact power of 2
        int lo = 0, hi = 0;
        lo = pk8<false>(a.x * S, a.y * S, lo); lo = pk8<true>(a.z * S, a.w * S, lo);
        hi = pk8<false>(b.x * S, b.y * S, hi); hi = pk8<true>(b.z * S, b.w * S, hi);
        *(int2*)(cb8 + (size_t)row * DIM + lane * 8) = make_int2(lo, hi);
        for (int m = 32; m; m >>= 1) ns += __shfl_down(ns, m, 64);
        if (lane == 0) enorm[row] = S * ns;      // 8192 * ||e||^2 (f32-exact norm)
    } else {
        size_t i = ((size_t)(blockIdx.x - K_CODES / 4) * 256 + tid) * 8;
        float4 a = *(const float4*)(z + i);
        float4 b = *(const float4*)(z + i + 4);
        int lo = 0, hi = 0;
        lo = pk8<false>(a.x, a.y, lo); lo = pk8<true>(a.z, a.w, lo);
        hi = pk8<false>(b.x, b.y, hi); hi = pk8<true>(b.z, b.w, hi);
        *(int2*)(z8 + i) = make_int2(lo, hi);
    }
}

// ---- kernel 2: MX-fp8 GEMM (128x128, 4 waves) + atomicMin argmin -------
// Core is R13-best byte-for-byte; epilogue writes via atomicMin.
__global__ __launch_bounds__(256, 2) void gemm_argmin(
    const unsigned char* __restrict__ z8, const unsigned char* __restrict__ cbb,
    const float* __restrict__ enorm, unsigned int* __restrict__ candMin)
{
    __shared__ alignas(32) unsigned char As[2 * BM * BK];  // 32 KB dbuf
    __shared__ alignas(32) unsigned char Bs[2 * BN * BK];  // 32 KB dbuf
    __shared__ float Es[BN];

    const int tid = threadIdx.x;
    const int lane = tid & 63;
    const int w = tid >> 6;             // 0..3
    // XCD remap: b&7 = XCD; XCD owns mtiles [xcd*16,xcd*16+16) (1MB A
    // slice, L2-hot); ktile advances every 128 blocks.
    const int b = blockIdx.x;
    const int xcd = b & 7;
    const int idx = b >> 3;             // 0..1023
    const int ktile = idx >> 4;         // 0..63
    const int mtile = xcd * 16 + (idx & 15);
    const int mbase = mtile * BM;
    const int nbase = ktile * BN;

    if (tid < BN) Es[tid] = enorm[nbase + tid];

    f32x4 acc[16];
#pragma unroll
    for (int i = 0; i < 16; ++i) acc[i] = (f32x4){0.f, 0.f, 0.f, 0.f};

    const int rA = lane >> 3;           // row within 8-row chunk
    const int jG = ((lane & 7) ^ rA) * 16;  // pre-swizzled global 16B chunk
    const int quad = lane >> 4;
    const int l15 = lane & 15;
    const int sw = l15 & 7;
    const int rw = (w >> 1) * 64;       // wave row quadrant
    const int cw = (w & 1) * 64;        // wave col quadrant
    // Chunks c0=(2q)^sw, c1=c0^1 = one aligned 32B block (R3-proven: the
    // per-lane half-swap is identical for A and B -> dot product exact).
    const int t32 = ((quad << 1) ^ (sw & 6)) * 16;

#define STAGE(buf, dt_) do {                                                  \
    _Pragma("unroll")                                                         \
    for (int i_ = 0; i_ < 4; ++i_) {                                          \
        int c_ = w * 4 + i_;                                                  \
        int row_ = c_ * 8 + rA;                                               \
        int col_ = (dt_) * BK + jG;                                           \
        gload_lds(z8 + (size_t)(mbase + row_) * DIM + col_,                   \
                  As + (buf) * (BM * BK) + c_ * 1024 + lane * 16);            \
        gload_lds(cbb + (size_t)(nbase + row_) * DIM + col_,                  \
                  Bs + (buf) * (BN * BK) + c_ * 1024 + lane * 16);            \
    } } while (0)

    STAGE(0, 0);
    __syncthreads();   // compiler drains vmcnt(0) before barrier -> buf0 ready

#pragma unroll 1
    for (int dt = 0; dt < 4; ++dt) {
        const int cur = dt & 1;
        if (dt < 3) STAGE(cur ^ 1, dt + 1);   // prefetch overlaps this compute
        const unsigned char* Ab = As + cur * (BM * BK);
        const unsigned char* Bb = Bs + cur * (BN * BK);
#pragma unroll
        for (int h = 0; h < 2; ++h) {         // 2 B frags live at a time
            i32x8 bf0 = *(const i32x8*)(Bb + (cw + (h * 2 + 0) * 16 + l15) * BK + t32);
            i32x8 bf1 = *(const i32x8*)(Bb + (cw + (h * 2 + 1) * 16 + l15) * BK + t32);
#pragma unroll
            for (int rf = 0; rf < 4; ++rf) {
                i32x8 a = *(const i32x8*)(Ab + (rw + rf * 16 + l15) * BK + t32);
                acc[rf * 4 + h * 2 + 0] = __builtin_amdgcn_mfma_scale_f32_16x16x128_f8f6f4(
                    a, bf0, acc[rf * 4 + h * 2 + 0],
                    0, 0, 0, 0x7F7F7F7F, 0, 0x7F7F7F7F);
                acc[rf * 4 + h * 2 + 1] = __builtin_amdgcn_mfma_scale_f32_16x16x128_f8f6f4(
                    a, bf1, acc[rf * 4 + h * 2 + 1],
                    0, 0, 0, 0x7F7F7F7F, 0, 0x7F7F7F7F);
            }
        }
        __syncthreads();   // reads done; prefetched buffer landed
    }
#undef STAGE

    // epilogue: per-row argmin over this tile's 128 cols -> atomicMin.
    // C/D layout: col = lane&15, row = quad*4 + reg.
    // Packed key: monotone-uint(dist), low 13 bits = global code index.
    float es[4];
#pragma unroll
    for (int cf = 0; cf < 4; ++cf) es[cf] = Es[cw + cf * 16 + l15];

#pragma unroll
    for (int rf = 0; rf < 4; ++rf) {
#pragma unroll
        for (int r = 0; r < 4; ++r) {
            float bv = 3.4e38f; int bi = 0;
#pragma unroll
            for (int cf = 0; cf < 4; ++cf) {
                int col = cw + cf * 16 + l15;
                float dist = fmaf(-2.0f, acc[rf * 4 + cf][r], es[cf]);
                if (dist < bv) { bv = dist; bi = col; }  // strict <: low col on tie
            }
            unsigned u = __builtin_bit_cast(unsigned, bv);
            u ^= ((unsigned)(((int)u) >> 31)) | 0x80000000u;
            unsigned key = (u & 0xFFFFE000u) | (unsigned)(nbase + bi);
#pragma unroll
            for (int m = 1; m < 16; m <<= 1) {
                unsigned o = __shfl_xor(key, m, 64);
                key = o < key ? o : key;
            }
            if (l15 == 0)
                atomicMin(&candMin[mbase + rw + rf * 16 + quad * 4 + r], key);
        }
    }
}

// ---- kernel 3: gather + ST output + loss atomic ------------------------
// Pure streaming now: per row one uniform key read, then 128 float4 slots.
// One plain atomicAdd per block for the loss.
__global__ __launch_bounds__(256) void gather_out(
    const float* __restrict__ z, const float* __restrict__ cb,
    const unsigned int* __restrict__ candMin, float* __restrict__ out)
{
    __shared__ float red[4];
    const int tid = threadIdx.x;
    const int w = tid >> 6, lane = tid & 63;
    float lsum = 0.f;
#pragma unroll
    for (int it = 0; it < M_ROWS / (GB_BLOCKS * 4); ++it) {
        int row = (it * GB_BLOCKS + blockIdx.x) * 4 + w;
        int k = (int)(candMin[row] & 8191u);    // uniform per wave
#pragma unroll
        for (int j = 0; j < 2; ++j) {
            int slot = lane + j * 64;
            float4 zv = ((const float4*)(z + (size_t)row * DIM))[slot];
            float4 cv = ((const float4*)(cb + (size_t)k * DIM))[slot];
            float dx = cv.x - zv.x, dy = cv.y - zv.y;
            float dz2 = cv.z - zv.z, dw = cv.w - zv.w;
            float4 o = {zv.x + dx, zv.y + dy, zv.z + dz2, zv.w + dw};  // z + sg(zq-z)
            ((float4*)(out + (size_t)row * DIM))[slot] = o;
            lsum += dx * dx + dy * dy + dz2 * dz2 + dw * dw;
        }
    }
    for (int m = 32; m; m >>= 1) lsum += __shfl_down(lsum, m, 64);
    if (lane == 0) red[w] = lsum;
    __syncthreads();
    if (tid == 0) {
        float t = (red[0] + red[1]) + (red[2] + red[3]);
        atomicAdd(out + OUT0_SIZE, t * (1.1f / (float)OUT0_SIZE));  // vq_loss = 1.1*mean
    }
}

extern "C" void kernel_launch(void* const* d_in, const int* in_sizes, int n_in,
                              void* d_out, int out_size, void* d_ws, size_t ws_size,
                              hipStream_t stream) {
    const float* z = (const float*)d_in[0];     // 16*1024*512
    const float* cb = (const float*)d_in[1];    // 8192*512
    float* out = (float*)d_out;                 // 8388608 + 1
    char* ws = (char*)d_ws;

    // ws layout (bytes)
    unsigned char* z8     = (unsigned char*)(ws);             //  8,388,608
    unsigned char* cb8    = (unsigned char*)(ws + 8388608);   //  4,194,304
    float* enorm          = (float*)(ws + 12582912);          //     32,768
    unsigned int* candMin = (unsigned int*)(ws + 12615680);   //     65,536

    convert_all<<<K_CODES / 4 + M_ROWS * DIM / 2048, 256, 0, stream>>>(
        z, cb, z8, cb8, enorm, candMin, out + OUT0_SIZE);
    gemm_argmin<<<NT * (M_ROWS / BM), 256, 0, stream>>>(z8, cb8, enorm, candMin);
    gather_out<<<GB_BLOCKS, 256, 0, stream>>>(z, cb, candMin, out);
}